// Round 1
// baseline (377.920 us; speedup 1.0000x reference)
//
#include <hip/hip_runtime.h>

#define N_NODES 50000
#define N_EDGES 800000
#define DIM 128
#define KTOT 256        // [agg | x] concatenated along k
#define N_GRAPHS 64
#define BUCKET_CAP 64
#define P_BLOCKS 512
#define LSTR 264        // LDS A-tile row stride in bf16 (+8 pad -> conflict-free b128)

// edge binning: bin = dst>>7 (128 nodes/bin), partitioned by blockIdx&7 (~XCD)
#define NBINS 391       // ceil(50000/128)
#define NPART 8
#define BINCAP 512      // mean 256/list, +16 sigma headroom
#define N_NODES_PAD (NBINS * 128)   // 50048

typedef __attribute__((ext_vector_type(8))) short bf16x8;
typedef __attribute__((ext_vector_type(16))) float f32x16;

__device__ __forceinline__ float bf2f(unsigned int u16) {
    return __uint_as_float(u16 << 16);
}
__device__ __forceinline__ unsigned short f2bf(float f) {
    unsigned int v = __float_as_uint(f);
    unsigned int r = (v + 0x7fffu + ((v >> 16) & 1u)) >> 16;   // RNE
    return (unsigned short)r;
}

// ---------- setup: casts ----------
// also zeros bincnt (must run before bin1_kernel)
__global__ void castx_kernel(const float* __restrict__ x, ushort* __restrict__ xb,
                             int* __restrict__ bincnt) {
    int i = blockIdx.x * blockDim.x + threadIdx.x;   // float4 index
    if (i < NPART * NBINS) bincnt[i] = 0;
    if (i >= N_NODES * DIM / 4) return;
    float4 v = ((const float4*)x)[i];
    ushort4 o;
    o.x = f2bf(v.x); o.y = f2bf(v.y); o.z = f2bf(v.z); o.w = f2bf(v.w);
    ((ushort4*)xb)[i] = o;
}

// wb layout per layer: [128 j][256 k] with k<128 = Wl, k>=128 = Wr. Also zeros pool.
__global__ void castw_kernel(const float* __restrict__ Wl0, const float* __restrict__ Wr0,
                             const float* __restrict__ Wl1, const float* __restrict__ Wr1,
                             const float* __restrict__ Wl2, const float* __restrict__ Wr2,
                             ushort* __restrict__ wb, float* __restrict__ pool) {
    int id = blockIdx.x * blockDim.x + threadIdx.x;   // 3*128*256 = 98304
    if (id < N_GRAPHS * DIM) pool[id] = 0.f;
    if (id >= 3 * DIM * KTOT) return;
    int l = id >> 15;
    int r = id & 32767;
    int j = r >> 8, k = r & 255;
    const float* Wl = (l == 0) ? Wl0 : (l == 1) ? Wl1 : Wl2;
    const float* Wr = (l == 0) ? Wr0 : (l == 1) ? Wr1 : Wr2;
    float v = (k < DIM) ? Wl[j * DIM + k] : Wr[j * DIM + k - DIM];
    wb[id] = f2bf(v);
}

// ---------- edge binning phase 1: coarse bins, XCD-local lists ----------
// Append packed (src | (dst&127)<<16) to list (part, dst>>7). Appends within a
// list are sequential positions written by one XCD -> L2 lines fill completely
// before eviction -> ~compact 3.2 MB write traffic (vs 44 MB scattered ushort).
__global__ void bin1_kernel(const int* __restrict__ src, const int* __restrict__ dst,
                            int* __restrict__ bincnt, uint* __restrict__ binbuf) {
    int e = blockIdx.x * blockDim.x + threadIdx.x;
    if (e >= N_EDGES) return;
    int part = blockIdx.x & (NPART - 1);     // ~XCD id (round-robin dispatch)
    int d = dst[e];
    int idx = part * NBINS + (d >> 7);
    int pos = atomicAdd(&bincnt[idx], 1);
    if (pos < BINCAP)
        binbuf[(size_t)idx * BINCAP + pos] = (uint)src[e] | ((uint)(d & 127) << 16);
}

// ---------- edge binning phase 2: LDS bucket build, coalesced flush ----------
// One block per bin (128 nodes). Replay the bin's edges through LDS atomics,
// then flush 16 KB of buckets + 128 counts with coalesced stores.
__global__ __launch_bounds__(256) void bin2_kernel(
    const uint* __restrict__ binbuf, const int* __restrict__ bincnt,
    ushort* __restrict__ bucket, int* __restrict__ cnt) {
    __shared__ int lcnt[128];
    __shared__ ushort lbuck[128 * BUCKET_CAP];   // 16 KB
    const int bin = blockIdx.x;
    const int tid = threadIdx.x;
    if (tid < 128) lcnt[tid] = 0;
    __syncthreads();
    #pragma unroll
    for (int p = 0; p < NPART; ++p) {
        int idx = p * NBINS + bin;
        int c = bincnt[idx];
        if (c > BINCAP) c = BINCAP;
        const uint* buf = binbuf + (size_t)idx * BINCAP;
        for (int i = tid; i < c; i += 256) {
            uint v = buf[i];
            int ln = v >> 16;
            int pos = atomicAdd(&lcnt[ln], 1);
            if (pos < BUCKET_CAP) lbuck[ln * BUCKET_CAP + pos] = (ushort)(v & 0xffffu);
        }
    }
    __syncthreads();
    // flush buckets: 128 rows x 64 ushort = 1024 uint4, coalesced
    const uint4* lb = (const uint4*)lbuck;
    uint4* gb = (uint4*)(bucket + (size_t)bin * 128 * BUCKET_CAP);
    #pragma unroll
    for (int i = tid; i < 128 * BUCKET_CAP / 8; i += 256)
        gb[i] = lb[i];
    if (tid < 128) cnt[bin * 128 + tid] = lcnt[tid];   // full count (incl. >64 overflow)
}

// ---------- pull aggregation (bf16 in/out, fp32 accum) ----------
// One wave per node. Lane owns 4 cols (8 B); half-wave 0 takes even edges,
// half-wave 1 odd edges -> one load instr fetches TWO rows; 4-deep unroll = 8
// rows in flight. Halves combined via __shfl_xor(.,32).
__global__ __launch_bounds__(256) void gather_kernel(
    const ushort* __restrict__ X, const int* __restrict__ cnt,
    const ushort* __restrict__ bucket, ushort* __restrict__ agg) {
    int n = (blockIdx.x * blockDim.x + threadIdx.x) >> 6;
    int lane = threadIdx.x & 63;
    if (n >= N_NODES) return;
    int c = cnt[n];
    int cl = c < BUCKET_CAP ? c : BUCKET_CAP;
    const ushort* b = bucket + (size_t)n * BUCKET_CAP;
    const int half = lane >> 5, lcol = lane & 31;
    float a0 = 0.f, a1 = 0.f, a2 = 0.f, a3 = 0.f;
    int e = half;
    for (; e + 6 < cl; e += 8) {
        int s0 = b[e], s1 = b[e + 2], s2 = b[e + 4], s3 = b[e + 6];
        uint2 u0 = *(const uint2*)(X + (size_t)s0 * DIM + lcol * 4);
        uint2 u1 = *(const uint2*)(X + (size_t)s1 * DIM + lcol * 4);
        uint2 u2 = *(const uint2*)(X + (size_t)s2 * DIM + lcol * 4);
        uint2 u3 = *(const uint2*)(X + (size_t)s3 * DIM + lcol * 4);
        a0 += bf2f(u0.x & 0xffff) + bf2f(u1.x & 0xffff) + bf2f(u2.x & 0xffff) + bf2f(u3.x & 0xffff);
        a1 += bf2f(u0.x >> 16)    + bf2f(u1.x >> 16)    + bf2f(u2.x >> 16)    + bf2f(u3.x >> 16);
        a2 += bf2f(u0.y & 0xffff) + bf2f(u1.y & 0xffff) + bf2f(u2.y & 0xffff) + bf2f(u3.y & 0xffff);
        a3 += bf2f(u0.y >> 16)    + bf2f(u1.y >> 16)    + bf2f(u2.y >> 16)    + bf2f(u3.y >> 16);
    }
    for (; e < cl; e += 2) {
        int s0 = b[e];
        uint2 u0 = *(const uint2*)(X + (size_t)s0 * DIM + lcol * 4);
        a0 += bf2f(u0.x & 0xffff);
        a1 += bf2f(u0.x >> 16);
        a2 += bf2f(u0.y & 0xffff);
        a3 += bf2f(u0.y >> 16);
    }
    a0 += __shfl_xor(a0, 32);
    a1 += __shfl_xor(a1, 32);
    a2 += __shfl_xor(a2, 32);
    a3 += __shfl_xor(a3, 32);
    if (half == 0) {
        float inv = 1.0f / (float)(c > 0 ? c : 1);
        uint2 o;
        o.x = ((unsigned int)f2bf(a1 * inv) << 16) | f2bf(a0 * inv);
        o.y = ((unsigned int)f2bf(a3 * inv) << 16) | f2bf(a2 * inv);
        *(uint2*)(agg + (size_t)n * DIM + lcol * 4) = o;
    }
}

// ---------- MFMA layer: out[50000x128] = [agg|h][50000x256] . W[128x256]^T ----------
__global__ __launch_bounds__(512, 4) void layer_mfma(
    const ushort* __restrict__ aggb, const ushort* __restrict__ hb,
    const ushort* __restrict__ wb, const float* __restrict__ bl,
    ushort* __restrict__ outb, int relu)
{
    __shared__ ushort sA[64 * LSTR];
    const int tid = threadIdx.x;
    const int lane = tid & 63, w = tid >> 6;
    const int mh = w & 1, jq = w >> 1;
    const int n0 = blockIdx.x * 64;

    // W fragments: lane l holds W[jq*32 + (l&31)][kt*16 + (l>>5)*8 .. +7]
    bf16x8 bw[16];
    {
        const ushort* wp = wb + (size_t)(jq * 32 + (lane & 31)) * KTOT + (lane >> 5) * 8;
        #pragma unroll
        for (int kt = 0; kt < 16; ++kt)
            bw[kt] = *(const bf16x8*)(wp + kt * 16);
    }

    // Stage A tile: 64 rows x 256 bf16 (k<128 from aggb, else hb)
    #pragma unroll
    for (int it = 0; it < 4; ++it) {
        int ci = tid + it * 512;
        int row = ci >> 5;
        int k8 = (ci & 31) * 8;
        int gn = n0 + row;
        bf16x8 v = (bf16x8){0,0,0,0,0,0,0,0};
        if (gn < N_NODES) {
            const ushort* p = (k8 < DIM) ? (aggb + (size_t)gn * DIM + k8)
                                         : (hb + (size_t)gn * DIM + (k8 - DIM));
            v = *(const bf16x8*)p;
        }
        *(bf16x8*)(&sA[row * LSTR + k8]) = v;
    }
    __syncthreads();

    f32x16 acc = {};
    const int arow = mh * 32 + (lane & 31);
    const int akoff = (lane >> 5) * 8;
    #pragma unroll
    for (int kt = 0; kt < 16; ++kt) {
        bf16x8 a = *(const bf16x8*)(&sA[arow * LSTR + kt * 16 + akoff]);
        acc = __builtin_amdgcn_mfma_f32_32x32x16_bf16(a, bw[kt], acc, 0, 0, 0);
    }

    // C/D map: col=lane&31, row=(reg&3)+8*(reg>>2)+4*(lane>>5)  [m74/m101]
    const int col = lane & 31;
    const int j = jq * 32 + col;
    const float bias = bl[j];
    #pragma unroll
    for (int r = 0; r < 16; ++r) {
        int row = (r & 3) + 8 * (r >> 2) + 4 * (lane >> 5);
        int gn = n0 + mh * 32 + row;
        if (gn < N_NODES) {
            float v = acc[r] + bias;
            if (relu) v = fmaxf(v, 0.f);
            outb[(size_t)gn * DIM + j] = f2bf(v);
        }
    }
}

// ---------- pool ----------
__global__ void pool1_kernel(const ushort* __restrict__ H, const int* __restrict__ batch,
                             float* __restrict__ pool) {
    const int per = (N_NODES + P_BLOCKS - 1) / P_BLOCKS;
    int n0 = blockIdx.x * per;
    int n1 = n0 + per; if (n1 > N_NODES) n1 = N_NODES;
    if (n0 >= n1) return;
    int j = threadIdx.x;
    float acc = 0.f;
    int g = batch[n0];
    for (int n = n0; n < n1; ++n) {
        int bg = batch[n];
        if (bg != g) {
            unsafeAtomicAdd(&pool[g * DIM + j], acc);
            acc = 0.f; g = bg;
        }
        acc += bf2f(H[(size_t)n * DIM + j]);
    }
    unsafeAtomicAdd(&pool[g * DIM + j], acc);
}

__global__ void pool2_kernel(const float* __restrict__ pool, const int* __restrict__ batch,
                             float* __restrict__ out) {
    int g = blockIdx.x;
    int j = threadIdx.x;
    int lo = 0, hi = N_NODES;
    while (lo < hi) { int m = (lo + hi) >> 1; if (batch[m] < g) lo = m + 1; else hi = m; }
    int start = lo;
    lo = start; hi = N_NODES;
    while (lo < hi) { int m = (lo + hi) >> 1; if (batch[m] < g + 1) lo = m + 1; else hi = m; }
    int cnt = lo - start;
    out[g * DIM + j] = pool[g * DIM + j] / (float)(cnt > 0 ? cnt : 1);
}

extern "C" void kernel_launch(void* const* d_in, const int* in_sizes, int n_in,
                              void* d_out, int out_size, void* d_ws, size_t ws_size,
                              hipStream_t stream) {
    const float* x    = (const float*)d_in[0];
    const int*   ei   = (const int*)d_in[1];
    const int*   src  = ei;
    const int*   dst  = ei + N_EDGES;
    const int*   batch = (const int*)d_in[2];
    const float* Wl0 = (const float*)d_in[3];
    const float* bl0 = (const float*)d_in[4];
    const float* Wr0 = (const float*)d_in[5];
    const float* Wl1 = (const float*)d_in[6];
    const float* bl1 = (const float*)d_in[7];
    const float* Wr1 = (const float*)d_in[8];
    const float* Wl2 = (const float*)d_in[9];
    const float* bl2 = (const float*)d_in[10];
    const float* Wr2 = (const float*)d_in[11];
    float* out = (float*)d_out;

    int*    cnt    = (int*)d_ws;                               // 65536 ints
    ushort* bucket = (ushort*)(cnt + 65536);                   // N_NODES_PAD*64 ushorts
    ushort* xb     = bucket + (size_t)N_NODES_PAD * BUCKET_CAP;
    ushort* aggb   = xb + (size_t)N_NODES * DIM;
    ushort* h1b    = aggb + (size_t)N_NODES * DIM;
    ushort* h2b    = h1b + (size_t)N_NODES * DIM;
    ushort* h3b    = h2b + (size_t)N_NODES * DIM;
    ushort* wb     = h3b + (size_t)N_NODES * DIM;              // 3 * 32768 bf16
    float*  pool   = (float*)(wb + 3 * DIM * KTOT);            // 8192 floats
    int*    bincnt = (int*)(pool + N_GRAPHS * DIM);            // NPART*NBINS ints
    uint*   binbuf = (uint*)aggb;   // aliased: 6.4 MB <= 12.8 MB, dead before gather

    castx_kernel<<<(N_NODES * DIM / 4 + 255) / 256, 256, 0, stream>>>(x, xb, bincnt);
    castw_kernel<<<(3 * DIM * KTOT + 255) / 256, 256, 0, stream>>>(Wl0, Wr0, Wl1, Wr1, Wl2, Wr2, wb, pool);
    bin1_kernel<<<(N_EDGES + 255) / 256, 256, 0, stream>>>(src, dst, bincnt, binbuf);
    bin2_kernel<<<NBINS, 256, 0, stream>>>(binbuf, bincnt, bucket, cnt);

    const int ggrid = (N_NODES * 64 + 255) / 256;
    const int lgrid = (N_NODES + 63) / 64;

    gather_kernel<<<ggrid, 256, 0, stream>>>(xb, cnt, bucket, aggb);
    layer_mfma<<<lgrid, 512, 0, stream>>>(aggb, xb, wb,          bl0, h1b, 1);
    gather_kernel<<<ggrid, 256, 0, stream>>>(h1b, cnt, bucket, aggb);
    layer_mfma<<<lgrid, 512, 0, stream>>>(aggb, h1b, wb + 32768, bl1, h2b, 1);
    gather_kernel<<<ggrid, 256, 0, stream>>>(h2b, cnt, bucket, aggb);
    layer_mfma<<<lgrid, 512, 0, stream>>>(aggb, h2b, wb + 65536, bl2, h3b, 0);

    pool1_kernel<<<P_BLOCKS, DIM, 0, stream>>>(h3b, batch, pool);
    pool2_kernel<<<N_GRAPHS, DIM, 0, stream>>>(pool, batch, out);
}

// Round 2
// 322.514 us; speedup vs baseline: 1.1718x; 1.1718x over previous
//
#include <hip/hip_runtime.h>

#define N_NODES 50000
#define N_EDGES 800000
#define DIM 128
#define KTOT 256        // [agg | x] concatenated along k
#define N_GRAPHS 64
#define BUCKET_CAP 64
#define P_BLOCKS 512
#define LSTR 264        // LDS A-tile row stride in bf16 (+8 pad -> conflict-free b128)

// edge binning: bin = dst>>7 (128 nodes/bin)
#define NBINS 391       // ceil(50000/128)
#define BINCAP2 2816    // per-bin list capacity (mean 2046, +17 sigma)
#define N_NODES_PAD (NBINS * 128)   // 50048

// bin1 geometry: 512 thr x 8 edges = 4096 edges/block -> 196 blocks
#define BIN1_TPB 512
#define BIN1_EPT 8
#define BIN1_EPB (BIN1_TPB * BIN1_EPT)
#define BIN1_GRID ((N_EDGES + BIN1_EPB - 1) / BIN1_EPB)

typedef __attribute__((ext_vector_type(8))) short bf16x8;
typedef __attribute__((ext_vector_type(16))) float f32x16;

__device__ __forceinline__ float bf2f(unsigned int u16) {
    return __uint_as_float(u16 << 16);
}
__device__ __forceinline__ unsigned short f2bf(float f) {
    unsigned int v = __float_as_uint(f);
    unsigned int r = (v + 0x7fffu + ((v >> 16) & 1u)) >> 16;   // RNE
    return (unsigned short)r;
}

// ---------- setup: casts ----------
// also zeros bincnt (must run before bin1_kernel)
__global__ void castx_kernel(const float* __restrict__ x, ushort* __restrict__ xb,
                             int* __restrict__ bincnt) {
    int i = blockIdx.x * blockDim.x + threadIdx.x;   // float4 index
    if (i < NBINS) bincnt[i] = 0;
    if (i >= N_NODES * DIM / 4) return;
    float4 v = ((const float4*)x)[i];
    ushort4 o;
    o.x = f2bf(v.x); o.y = f2bf(v.y); o.z = f2bf(v.z); o.w = f2bf(v.w);
    ((ushort4*)xb)[i] = o;
}

// wb layout per layer: [128 j][256 k] with k<128 = Wl, k>=128 = Wr. Also zeros pool.
__global__ void castw_kernel(const float* __restrict__ Wl0, const float* __restrict__ Wr0,
                             const float* __restrict__ Wl1, const float* __restrict__ Wr1,
                             const float* __restrict__ Wl2, const float* __restrict__ Wr2,
                             ushort* __restrict__ wb, float* __restrict__ pool) {
    int id = blockIdx.x * blockDim.x + threadIdx.x;   // 3*128*256 = 98304
    if (id < N_GRAPHS * DIM) pool[id] = 0.f;
    if (id >= 3 * DIM * KTOT) return;
    int l = id >> 15;
    int r = id & 32767;
    int j = r >> 8, k = r & 255;
    const float* Wl = (l == 0) ? Wl0 : (l == 1) ? Wl1 : Wl2;
    const float* Wr = (l == 0) ? Wr0 : (l == 1) ? Wr1 : Wr2;
    float v = (k < DIM) ? Wl[j * DIM + k] : Wr[j * DIM + k - DIM];
    wb[id] = f2bf(v);
}

// ---------- edge binning phase 1: LDS-ranked block partition ----------
// Per block: private LDS histogram of bins (LDS atomics give intra-block rank),
// ONE global atomicAdd per (block,bin) to reserve a contiguous run, then write
// the run. 77K global atomics total (vs 800K), each amortized over ~10 edges;
// runs are written by one block in one burst -> lines merge in L2.
__global__ __launch_bounds__(BIN1_TPB) void bin1_kernel(
    const int* __restrict__ src, const int* __restrict__ dst,
    int* __restrict__ bincnt, uint* __restrict__ binbuf) {
    __shared__ uint hist[NBINS];
    __shared__ uint gbase[NBINS];
    const int tid = threadIdx.x;
    for (int i = tid; i < NBINS; i += BIN1_TPB) hist[i] = 0;
    __syncthreads();

    const int e0 = blockIdx.x * BIN1_EPB + tid * BIN1_EPT;
    uint val[BIN1_EPT];
    int  bin[BIN1_EPT];
    uint rk[BIN1_EPT];

    if (e0 + BIN1_EPT <= N_EDGES) {
        int4 s0 = *(const int4*)(src + e0);
        int4 s1 = *(const int4*)(src + e0 + 4);
        int4 d0 = *(const int4*)(dst + e0);
        int4 d1 = *(const int4*)(dst + e0 + 4);
        int ss[8] = {s0.x, s0.y, s0.z, s0.w, s1.x, s1.y, s1.z, s1.w};
        int dd[8] = {d0.x, d0.y, d0.z, d0.w, d1.x, d1.y, d1.z, d1.w};
        #pragma unroll
        for (int i = 0; i < BIN1_EPT; ++i) {
            bin[i] = dd[i] >> 7;
            val[i] = (uint)ss[i] | ((uint)(dd[i] & 127) << 16);
            rk[i]  = atomicAdd(&hist[bin[i]], 1u);
        }
    } else {
        #pragma unroll
        for (int i = 0; i < BIN1_EPT; ++i) {
            if (e0 + i < N_EDGES) {
                int s = src[e0 + i], d = dst[e0 + i];
                bin[i] = d >> 7;
                val[i] = (uint)s | ((uint)(d & 127) << 16);
                rk[i]  = atomicAdd(&hist[bin[i]], 1u);
            } else {
                bin[i] = -1; val[i] = 0; rk[i] = 0;
            }
        }
    }
    __syncthreads();

    for (int i = tid; i < NBINS; i += BIN1_TPB)
        gbase[i] = (uint)atomicAdd(&bincnt[i], (int)hist[i]);
    __syncthreads();

    #pragma unroll
    for (int i = 0; i < BIN1_EPT; ++i) {
        if (bin[i] >= 0) {
            uint pos = gbase[bin[i]] + rk[i];
            if (pos < BINCAP2)
                binbuf[(size_t)bin[i] * BINCAP2 + pos] = val[i];
        }
    }
}

// ---------- edge binning phase 2: LDS bucket build, coalesced flush ----------
// One block per bin (128 nodes). Replay the bin's ~2046 edges through LDS
// atomics, then flush 16 KB of buckets + 128 counts with coalesced stores.
__global__ __launch_bounds__(256) void bin2_kernel(
    const uint* __restrict__ binbuf, const int* __restrict__ bincnt,
    ushort* __restrict__ bucket, int* __restrict__ cnt) {
    __shared__ int lcnt[128];
    __shared__ ushort lbuck[128 * BUCKET_CAP];   // 16 KB
    const int bin = blockIdx.x;
    const int tid = threadIdx.x;
    if (tid < 128) lcnt[tid] = 0;
    __syncthreads();
    int c = bincnt[bin];
    if (c > BINCAP2) c = BINCAP2;
    const uint* buf = binbuf + (size_t)bin * BINCAP2;
    for (int i = tid; i < c; i += 256) {
        uint v = buf[i];
        int ln = v >> 16;
        int pos = atomicAdd(&lcnt[ln], 1);
        if (pos < BUCKET_CAP) lbuck[ln * BUCKET_CAP + pos] = (ushort)(v & 0xffffu);
    }
    __syncthreads();
    // flush buckets: 128 rows x 64 ushort = 1024 uint4, coalesced
    const uint4* lb = (const uint4*)lbuck;
    uint4* gb = (uint4*)(bucket + (size_t)bin * 128 * BUCKET_CAP);
    #pragma unroll
    for (int i = tid; i < 128 * BUCKET_CAP / 8; i += 256)
        gb[i] = lb[i];
    if (tid < 128) cnt[bin * 128 + tid] = lcnt[tid];   // true degree (incl. >64 overflow)
}

// ---------- pull aggregation (bf16 in/out, fp32 accum) ----------
// One wave per node. Lane owns 4 cols (8 B); half-wave 0 takes even edges,
// half-wave 1 odd edges -> one load instr fetches TWO rows; 4-deep unroll = 8
// rows in flight. Halves combined via __shfl_xor(.,32).
__global__ __launch_bounds__(256) void gather_kernel(
    const ushort* __restrict__ X, const int* __restrict__ cnt,
    const ushort* __restrict__ bucket, ushort* __restrict__ agg) {
    int n = (blockIdx.x * blockDim.x + threadIdx.x) >> 6;
    int lane = threadIdx.x & 63;
    if (n >= N_NODES) return;
    int c = cnt[n];
    int cl = c < BUCKET_CAP ? c : BUCKET_CAP;
    const ushort* b = bucket + (size_t)n * BUCKET_CAP;
    const int half = lane >> 5, lcol = lane & 31;
    float a0 = 0.f, a1 = 0.f, a2 = 0.f, a3 = 0.f;
    int e = half;
    for (; e + 6 < cl; e += 8) {
        int s0 = b[e], s1 = b[e + 2], s2 = b[e + 4], s3 = b[e + 6];
        uint2 u0 = *(const uint2*)(X + (size_t)s0 * DIM + lcol * 4);
        uint2 u1 = *(const uint2*)(X + (size_t)s1 * DIM + lcol * 4);
        uint2 u2 = *(const uint2*)(X + (size_t)s2 * DIM + lcol * 4);
        uint2 u3 = *(const uint2*)(X + (size_t)s3 * DIM + lcol * 4);
        a0 += bf2f(u0.x & 0xffff) + bf2f(u1.x & 0xffff) + bf2f(u2.x & 0xffff) + bf2f(u3.x & 0xffff);
        a1 += bf2f(u0.x >> 16)    + bf2f(u1.x >> 16)    + bf2f(u2.x >> 16)    + bf2f(u3.x >> 16);
        a2 += bf2f(u0.y & 0xffff) + bf2f(u1.y & 0xffff) + bf2f(u2.y & 0xffff) + bf2f(u3.y & 0xffff);
        a3 += bf2f(u0.y >> 16)    + bf2f(u1.y >> 16)    + bf2f(u2.y >> 16)    + bf2f(u3.y >> 16);
    }
    for (; e < cl; e += 2) {
        int s0 = b[e];
        uint2 u0 = *(const uint2*)(X + (size_t)s0 * DIM + lcol * 4);
        a0 += bf2f(u0.x & 0xffff);
        a1 += bf2f(u0.x >> 16);
        a2 += bf2f(u0.y & 0xffff);
        a3 += bf2f(u0.y >> 16);
    }
    a0 += __shfl_xor(a0, 32);
    a1 += __shfl_xor(a1, 32);
    a2 += __shfl_xor(a2, 32);
    a3 += __shfl_xor(a3, 32);
    if (half == 0) {
        float inv = 1.0f / (float)(c > 0 ? c : 1);
        uint2 o;
        o.x = ((unsigned int)f2bf(a1 * inv) << 16) | f2bf(a0 * inv);
        o.y = ((unsigned int)f2bf(a3 * inv) << 16) | f2bf(a2 * inv);
        *(uint2*)(agg + (size_t)n * DIM + lcol * 4) = o;
    }
}

// ---------- MFMA layer: out[50000x128] = [agg|h][50000x256] . W[128x256]^T ----------
__global__ __launch_bounds__(512, 4) void layer_mfma(
    const ushort* __restrict__ aggb, const ushort* __restrict__ hb,
    const ushort* __restrict__ wb, const float* __restrict__ bl,
    ushort* __restrict__ outb, int relu)
{
    __shared__ ushort sA[64 * LSTR];
    const int tid = threadIdx.x;
    const int lane = tid & 63, w = tid >> 6;
    const int mh = w & 1, jq = w >> 1;
    const int n0 = blockIdx.x * 64;

    // W fragments: lane l holds W[jq*32 + (l&31)][kt*16 + (l>>5)*8 .. +7]
    bf16x8 bw[16];
    {
        const ushort* wp = wb + (size_t)(jq * 32 + (lane & 31)) * KTOT + (lane >> 5) * 8;
        #pragma unroll
        for (int kt = 0; kt < 16; ++kt)
            bw[kt] = *(const bf16x8*)(wp + kt * 16);
    }

    // Stage A tile: 64 rows x 256 bf16 (k<128 from aggb, else hb)
    #pragma unroll
    for (int it = 0; it < 4; ++it) {
        int ci = tid + it * 512;
        int row = ci >> 5;
        int k8 = (ci & 31) * 8;
        int gn = n0 + row;
        bf16x8 v = (bf16x8){0,0,0,0,0,0,0,0};
        if (gn < N_NODES) {
            const ushort* p = (k8 < DIM) ? (aggb + (size_t)gn * DIM + k8)
                                         : (hb + (size_t)gn * DIM + (k8 - DIM));
            v = *(const bf16x8*)p;
        }
        *(bf16x8*)(&sA[row * LSTR + k8]) = v;
    }
    __syncthreads();

    f32x16 acc = {};
    const int arow = mh * 32 + (lane & 31);
    const int akoff = (lane >> 5) * 8;
    #pragma unroll
    for (int kt = 0; kt < 16; ++kt) {
        bf16x8 a = *(const bf16x8*)(&sA[arow * LSTR + kt * 16 + akoff]);
        acc = __builtin_amdgcn_mfma_f32_32x32x16_bf16(a, bw[kt], acc, 0, 0, 0);
    }

    // C/D map: col=lane&31, row=(reg&3)+8*(reg>>2)+4*(lane>>5)  [m74/m101]
    const int col = lane & 31;
    const int j = jq * 32 + col;
    const float bias = bl[j];
    #pragma unroll
    for (int r = 0; r < 16; ++r) {
        int row = (r & 3) + 8 * (r >> 2) + 4 * (lane >> 5);
        int gn = n0 + mh * 32 + row;
        if (gn < N_NODES) {
            float v = acc[r] + bias;
            if (relu) v = fmaxf(v, 0.f);
            outb[(size_t)gn * DIM + j] = f2bf(v);
        }
    }
}

// ---------- pool ----------
__global__ void pool1_kernel(const ushort* __restrict__ H, const int* __restrict__ batch,
                             float* __restrict__ pool) {
    const int per = (N_NODES + P_BLOCKS - 1) / P_BLOCKS;
    int n0 = blockIdx.x * per;
    int n1 = n0 + per; if (n1 > N_NODES) n1 = N_NODES;
    if (n0 >= n1) return;
    int j = threadIdx.x;
    float acc = 0.f;
    int g = batch[n0];
    for (int n = n0; n < n1; ++n) {
        int bg = batch[n];
        if (bg != g) {
            unsafeAtomicAdd(&pool[g * DIM + j], acc);
            acc = 0.f; g = bg;
        }
        acc += bf2f(H[(size_t)n * DIM + j]);
    }
    unsafeAtomicAdd(&pool[g * DIM + j], acc);
}

__global__ void pool2_kernel(const float* __restrict__ pool, const int* __restrict__ batch,
                             float* __restrict__ out) {
    int g = blockIdx.x;
    int j = threadIdx.x;
    int lo = 0, hi = N_NODES;
    while (lo < hi) { int m = (lo + hi) >> 1; if (batch[m] < g) lo = m + 1; else hi = m; }
    int start = lo;
    lo = start; hi = N_NODES;
    while (lo < hi) { int m = (lo + hi) >> 1; if (batch[m] < g + 1) lo = m + 1; else hi = m; }
    int cnt = lo - start;
    out[g * DIM + j] = pool[g * DIM + j] / (float)(cnt > 0 ? cnt : 1);
}

extern "C" void kernel_launch(void* const* d_in, const int* in_sizes, int n_in,
                              void* d_out, int out_size, void* d_ws, size_t ws_size,
                              hipStream_t stream) {
    const float* x    = (const float*)d_in[0];
    const int*   ei   = (const int*)d_in[1];
    const int*   src  = ei;
    const int*   dst  = ei + N_EDGES;
    const int*   batch = (const int*)d_in[2];
    const float* Wl0 = (const float*)d_in[3];
    const float* bl0 = (const float*)d_in[4];
    const float* Wr0 = (const float*)d_in[5];
    const float* Wl1 = (const float*)d_in[6];
    const float* bl1 = (const float*)d_in[7];
    const float* Wr1 = (const float*)d_in[8];
    const float* Wl2 = (const float*)d_in[9];
    const float* bl2 = (const float*)d_in[10];
    const float* Wr2 = (const float*)d_in[11];
    float* out = (float*)d_out;

    int*    cnt    = (int*)d_ws;                               // 65536 ints
    ushort* bucket = (ushort*)(cnt + 65536);                   // N_NODES_PAD*64 ushorts
    ushort* xb     = bucket + (size_t)N_NODES_PAD * BUCKET_CAP;
    ushort* aggb   = xb + (size_t)N_NODES * DIM;
    ushort* h1b    = aggb + (size_t)N_NODES * DIM;
    ushort* h2b    = h1b + (size_t)N_NODES * DIM;
    ushort* h3b    = h2b + (size_t)N_NODES * DIM;
    ushort* wb     = h3b + (size_t)N_NODES * DIM;              // 3 * 32768 bf16
    float*  pool   = (float*)(wb + 3 * DIM * KTOT);            // 8192 floats
    int*    bincnt = (int*)(pool + N_GRAPHS * DIM);            // NBINS ints
    uint*   binbuf = (uint*)aggb;   // aliased: 4.4 MB <= 12.8 MB, dead before gather

    castx_kernel<<<(N_NODES * DIM / 4 + 255) / 256, 256, 0, stream>>>(x, xb, bincnt);
    castw_kernel<<<(3 * DIM * KTOT + 255) / 256, 256, 0, stream>>>(Wl0, Wr0, Wl1, Wr1, Wl2, Wr2, wb, pool);
    bin1_kernel<<<BIN1_GRID, BIN1_TPB, 0, stream>>>(src, dst, bincnt, binbuf);
    bin2_kernel<<<NBINS, 256, 0, stream>>>(binbuf, bincnt, bucket, cnt);

    const int ggrid = (N_NODES * 64 + 255) / 256;
    const int lgrid = (N_NODES + 63) / 64;

    gather_kernel<<<ggrid, 256, 0, stream>>>(xb, cnt, bucket, aggb);
    layer_mfma<<<lgrid, 512, 0, stream>>>(aggb, xb, wb,          bl0, h1b, 1);
    gather_kernel<<<ggrid, 256, 0, stream>>>(h1b, cnt, bucket, aggb);
    layer_mfma<<<lgrid, 512, 0, stream>>>(aggb, h1b, wb + 32768, bl1, h2b, 1);
    gather_kernel<<<ggrid, 256, 0, stream>>>(h2b, cnt, bucket, aggb);
    layer_mfma<<<lgrid, 512, 0, stream>>>(aggb, h2b, wb + 65536, bl2, h3b, 0);

    pool1_kernel<<<P_BLOCKS, DIM, 0, stream>>>(h3b, batch, pool);
    pool2_kernel<<<N_GRAPHS, DIM, 0, stream>>>(pool, batch, out);
}

// Round 3
// 273.274 us; speedup vs baseline: 1.3829x; 1.1802x over previous
//
#include <hip/hip_runtime.h>

#define N_NODES 50000
#define N_EDGES 800000
#define DIM 128
#define KTOT 256        // [agg | x] concatenated along k
#define N_GRAPHS 64
#define BUCKET_CAP 64
#define LSTR 264        // LDS A-tile row stride in bf16 (+8 pad -> conflict-free b128)

// edge binning: bin = dst>>7 (128 nodes/bin)
#define NBINS 391       // ceil(50000/128)
#define BINCAP2 2816    // per-bin list capacity (mean 2046, +17 sigma)
#define N_NODES_PAD (NBINS * 128)   // 50048

// bin1 geometry: 512 thr x 8 edges = 4096 edges/block -> 196 blocks
#define BIN1_TPB 512
#define BIN1_EPT 8
#define BIN1_EPB (BIN1_TPB * BIN1_EPT)
#define BIN1_GRID ((N_EDGES + BIN1_EPB - 1) / BIN1_EPB)

typedef __attribute__((ext_vector_type(8))) short bf16x8;
typedef __attribute__((ext_vector_type(16))) float f32x16;

__device__ __forceinline__ float bf2f(unsigned int u16) {
    return __uint_as_float(u16 << 16);
}
__device__ __forceinline__ unsigned short f2bf(float f) {
    unsigned int v = __float_as_uint(f);
    unsigned int r = (v + 0x7fffu + ((v >> 16) & 1u)) >> 16;   // RNE
    return (unsigned short)r;
}

// ---------- setup: casts ----------
// also zeros bincnt (must run before bin1_kernel)
__global__ void castx_kernel(const float* __restrict__ x, ushort* __restrict__ xb,
                             int* __restrict__ bincnt) {
    int i = blockIdx.x * blockDim.x + threadIdx.x;   // float4 index
    if (i < NBINS) bincnt[i] = 0;
    if (i >= N_NODES * DIM / 4) return;
    float4 v = ((const float4*)x)[i];
    ushort4 o;
    o.x = f2bf(v.x); o.y = f2bf(v.y); o.z = f2bf(v.z); o.w = f2bf(v.w);
    ((ushort4*)xb)[i] = o;
}

// wb layout per layer: [128 j][256 k] with k<128 = Wl, k>=128 = Wr. Also zeros pool.
__global__ void castw_kernel(const float* __restrict__ Wl0, const float* __restrict__ Wr0,
                             const float* __restrict__ Wl1, const float* __restrict__ Wr1,
                             const float* __restrict__ Wl2, const float* __restrict__ Wr2,
                             ushort* __restrict__ wb, float* __restrict__ pool) {
    int id = blockIdx.x * blockDim.x + threadIdx.x;   // 3*128*256 = 98304
    if (id < N_GRAPHS * DIM) pool[id] = 0.f;
    if (id >= 3 * DIM * KTOT) return;
    int l = id >> 15;
    int r = id & 32767;
    int j = r >> 8, k = r & 255;
    const float* Wl = (l == 0) ? Wl0 : (l == 1) ? Wl1 : Wl2;
    const float* Wr = (l == 0) ? Wr0 : (l == 1) ? Wr1 : Wr2;
    float v = (k < DIM) ? Wl[j * DIM + k] : Wr[j * DIM + k - DIM];
    wb[id] = f2bf(v);
}

// ---------- edge binning phase 1: LDS-ranked block partition ----------
__global__ __launch_bounds__(BIN1_TPB) void bin1_kernel(
    const int* __restrict__ src, const int* __restrict__ dst,
    int* __restrict__ bincnt, uint* __restrict__ binbuf) {
    __shared__ uint hist[NBINS];
    __shared__ uint gbase[NBINS];
    const int tid = threadIdx.x;
    for (int i = tid; i < NBINS; i += BIN1_TPB) hist[i] = 0;
    __syncthreads();

    const int e0 = blockIdx.x * BIN1_EPB + tid * BIN1_EPT;
    uint val[BIN1_EPT];
    int  bin[BIN1_EPT];
    uint rk[BIN1_EPT];

    if (e0 + BIN1_EPT <= N_EDGES) {
        int4 s0 = *(const int4*)(src + e0);
        int4 s1 = *(const int4*)(src + e0 + 4);
        int4 d0 = *(const int4*)(dst + e0);
        int4 d1 = *(const int4*)(dst + e0 + 4);
        int ss[8] = {s0.x, s0.y, s0.z, s0.w, s1.x, s1.y, s1.z, s1.w};
        int dd[8] = {d0.x, d0.y, d0.z, d0.w, d1.x, d1.y, d1.z, d1.w};
        #pragma unroll
        for (int i = 0; i < BIN1_EPT; ++i) {
            bin[i] = dd[i] >> 7;
            val[i] = (uint)ss[i] | ((uint)(dd[i] & 127) << 16);
            rk[i]  = atomicAdd(&hist[bin[i]], 1u);
        }
    } else {
        #pragma unroll
        for (int i = 0; i < BIN1_EPT; ++i) {
            if (e0 + i < N_EDGES) {
                int s = src[e0 + i], d = dst[e0 + i];
                bin[i] = d >> 7;
                val[i] = (uint)s | ((uint)(d & 127) << 16);
                rk[i]  = atomicAdd(&hist[bin[i]], 1u);
            } else {
                bin[i] = -1; val[i] = 0; rk[i] = 0;
            }
        }
    }
    __syncthreads();

    for (int i = tid; i < NBINS; i += BIN1_TPB)
        gbase[i] = (uint)atomicAdd(&bincnt[i], (int)hist[i]);
    __syncthreads();

    #pragma unroll
    for (int i = 0; i < BIN1_EPT; ++i) {
        if (bin[i] >= 0) {
            uint pos = gbase[bin[i]] + rk[i];
            if (pos < BINCAP2)
                binbuf[(size_t)bin[i] * BINCAP2 + pos] = val[i];
        }
    }
}

// ---------- edge binning phase 2: LDS bucket build, coalesced flush ----------
__global__ __launch_bounds__(256) void bin2_kernel(
    const uint* __restrict__ binbuf, const int* __restrict__ bincnt,
    ushort* __restrict__ bucket, int* __restrict__ cnt) {
    __shared__ int lcnt[128];
    __shared__ ushort lbuck[128 * BUCKET_CAP];   // 16 KB
    const int bin = blockIdx.x;
    const int tid = threadIdx.x;
    if (tid < 128) lcnt[tid] = 0;
    __syncthreads();
    int c = bincnt[bin];
    if (c > BINCAP2) c = BINCAP2;
    const uint* buf = binbuf + (size_t)bin * BINCAP2;
    for (int i = tid; i < c; i += 256) {
        uint v = buf[i];
        int ln = v >> 16;
        int pos = atomicAdd(&lcnt[ln], 1);
        if (pos < BUCKET_CAP) lbuck[ln * BUCKET_CAP + pos] = (ushort)(v & 0xffffu);
    }
    __syncthreads();
    const uint4* lb = (const uint4*)lbuck;
    uint4* gb = (uint4*)(bucket + (size_t)bin * 128 * BUCKET_CAP);
    #pragma unroll
    for (int i = tid; i < 128 * BUCKET_CAP / 8; i += 256)
        gb[i] = lb[i];
    if (tid < 128) cnt[bin * 128 + tid] = lcnt[tid];   // true degree (incl. >64 overflow)
}

// ---------- fused gather + MFMA layer ----------
// Block = 64 nodes, 512 threads (8 waves). Wave w gathers nodes w*8..w*8+7:
// lane owns 4 cols; half-wave 0 even edges, half-wave 1 odd edges; halves
// combined via __shfl_xor(.,32); mean written straight into LDS A-tile k<128.
// k>=128 half staged from X (the node's own features). Then 32x32x16 MFMA.
// POOL=1 (layer 3): skip h store; lane run-flushes its 16 rows (ascending,
// batch sorted) into pool with ~1-2 unsafeAtomicAdd.
template<int RELU, int POOL>
__global__ __launch_bounds__(512, 4) void layer_fused(
    const ushort* __restrict__ X, const int* __restrict__ cnt,
    const ushort* __restrict__ bucket, const ushort* __restrict__ wb,
    const float* __restrict__ bl, ushort* __restrict__ outb,
    const int* __restrict__ batch, float* __restrict__ pool)
{
    __shared__ ushort sA[64 * LSTR];
    const int tid = threadIdx.x;
    const int lane = tid & 63, w = tid >> 6;
    const int mh = w & 1, jq = w >> 1;
    const int n0 = blockIdx.x * 64;
    const int half = lane >> 5, lcol = lane & 31;

    // ---- stage h half (k>=128): 64 rows x 128 cols, coalesced ----
    #pragma unroll
    for (int it = 0; it < 2; ++it) {
        int ci = tid + it * 512;
        int row = ci >> 4;
        int k8 = (ci & 15) * 8;
        int gn = n0 + row;
        bf16x8 v = (bf16x8){0,0,0,0,0,0,0,0};
        if (gn < N_NODES) v = *(const bf16x8*)(X + (size_t)gn * DIM + k8);
        *(bf16x8*)(&sA[row * LSTR + DIM + k8]) = v;
    }

    // ---- gather agg half (k<128): wave w owns rows w*8 .. w*8+7 ----
    for (int r8 = 0; r8 < 8; ++r8) {
        const int row = w * 8 + r8;
        const int gn = n0 + row;
        float a0 = 0.f, a1 = 0.f, a2 = 0.f, a3 = 0.f;
        int c = 0;
        if (gn < N_NODES) {
            c = cnt[gn];
            int cl = c < BUCKET_CAP ? c : BUCKET_CAP;
            const ushort* b = bucket + (size_t)gn * BUCKET_CAP;
            int e = half;
            for (; e + 6 < cl; e += 8) {
                int s0 = b[e], s1 = b[e + 2], s2 = b[e + 4], s3 = b[e + 6];
                uint2 u0 = *(const uint2*)(X + (size_t)s0 * DIM + lcol * 4);
                uint2 u1 = *(const uint2*)(X + (size_t)s1 * DIM + lcol * 4);
                uint2 u2 = *(const uint2*)(X + (size_t)s2 * DIM + lcol * 4);
                uint2 u3 = *(const uint2*)(X + (size_t)s3 * DIM + lcol * 4);
                a0 += bf2f(u0.x & 0xffff) + bf2f(u1.x & 0xffff) + bf2f(u2.x & 0xffff) + bf2f(u3.x & 0xffff);
                a1 += bf2f(u0.x >> 16)    + bf2f(u1.x >> 16)    + bf2f(u2.x >> 16)    + bf2f(u3.x >> 16);
                a2 += bf2f(u0.y & 0xffff) + bf2f(u1.y & 0xffff) + bf2f(u2.y & 0xffff) + bf2f(u3.y & 0xffff);
                a3 += bf2f(u0.y >> 16)    + bf2f(u1.y >> 16)    + bf2f(u2.y >> 16)    + bf2f(u3.y >> 16);
            }
            for (; e < cl; e += 2) {
                int s0 = b[e];
                uint2 u0 = *(const uint2*)(X + (size_t)s0 * DIM + lcol * 4);
                a0 += bf2f(u0.x & 0xffff);
                a1 += bf2f(u0.x >> 16);
                a2 += bf2f(u0.y & 0xffff);
                a3 += bf2f(u0.y >> 16);
            }
        }
        a0 += __shfl_xor(a0, 32);
        a1 += __shfl_xor(a1, 32);
        a2 += __shfl_xor(a2, 32);
        a3 += __shfl_xor(a3, 32);
        if (half == 0) {
            float inv = 1.0f / (float)(c > 0 ? c : 1);
            uint2 o;
            o.x = ((unsigned int)f2bf(a1 * inv) << 16) | f2bf(a0 * inv);
            o.y = ((unsigned int)f2bf(a3 * inv) << 16) | f2bf(a2 * inv);
            *(uint2*)(&sA[row * LSTR + lcol * 4]) = o;
        }
    }
    __syncthreads();

    // ---- W fragments (loaded after gather to keep gather-phase VGPR low) ----
    // lane l holds W[jq*32 + (l&31)][kt*16 + (l>>5)*8 .. +7]
    bf16x8 bw[16];
    {
        const ushort* wp = wb + (size_t)(jq * 32 + (lane & 31)) * KTOT + (lane >> 5) * 8;
        #pragma unroll
        for (int kt = 0; kt < 16; ++kt)
            bw[kt] = *(const bf16x8*)(wp + kt * 16);
    }

    f32x16 acc = {};
    const int arow = mh * 32 + (lane & 31);
    const int akoff = (lane >> 5) * 8;
    #pragma unroll
    for (int kt = 0; kt < 16; ++kt) {
        bf16x8 a = *(const bf16x8*)(&sA[arow * LSTR + kt * 16 + akoff]);
        acc = __builtin_amdgcn_mfma_f32_32x32x16_bf16(a, bw[kt], acc, 0, 0, 0);
    }

    // C/D map: col=lane&31, row=(reg&3)+8*(reg>>2)+4*(lane>>5)  [m74/m101]
    const int j = jq * 32 + (lane & 31);
    const float bias = bl[j];
    if (POOL) {
        // rows ascend with r -> run-flush per graph segment
        float run = 0.f; int gcur = -1;
        #pragma unroll
        for (int r = 0; r < 16; ++r) {
            int row = (r & 3) + 8 * (r >> 2) + 4 * (lane >> 5);
            int gn = n0 + mh * 32 + row;
            if (gn < N_NODES) {
                float v = acc[r] + bias;
                int g = batch[gn];
                if (g != gcur) {
                    if (gcur >= 0) unsafeAtomicAdd(&pool[gcur * DIM + j], run);
                    run = 0.f; gcur = g;
                }
                run += v;
            }
        }
        if (gcur >= 0) unsafeAtomicAdd(&pool[gcur * DIM + j], run);
    } else {
        #pragma unroll
        for (int r = 0; r < 16; ++r) {
            int row = (r & 3) + 8 * (r >> 2) + 4 * (lane >> 5);
            int gn = n0 + mh * 32 + row;
            if (gn < N_NODES) {
                float v = acc[r] + bias;
                if (RELU) v = fmaxf(v, 0.f);
                outb[(size_t)gn * DIM + j] = f2bf(v);
            }
        }
    }
}

// ---------- pool finalize ----------
__global__ void pool2_kernel(const float* __restrict__ pool, const int* __restrict__ batch,
                             float* __restrict__ out) {
    int g = blockIdx.x;
    int j = threadIdx.x;
    int lo = 0, hi = N_NODES;
    while (lo < hi) { int m = (lo + hi) >> 1; if (batch[m] < g) lo = m + 1; else hi = m; }
    int start = lo;
    lo = start; hi = N_NODES;
    while (lo < hi) { int m = (lo + hi) >> 1; if (batch[m] < g + 1) lo = m + 1; else hi = m; }
    int cnt = lo - start;
    out[g * DIM + j] = pool[g * DIM + j] / (float)(cnt > 0 ? cnt : 1);
}

extern "C" void kernel_launch(void* const* d_in, const int* in_sizes, int n_in,
                              void* d_out, int out_size, void* d_ws, size_t ws_size,
                              hipStream_t stream) {
    const float* x    = (const float*)d_in[0];
    const int*   ei   = (const int*)d_in[1];
    const int*   src  = ei;
    const int*   dst  = ei + N_EDGES;
    const int*   batch = (const int*)d_in[2];
    const float* Wl0 = (const float*)d_in[3];
    const float* bl0 = (const float*)d_in[4];
    const float* Wr0 = (const float*)d_in[5];
    const float* Wl1 = (const float*)d_in[6];
    const float* bl1 = (const float*)d_in[7];
    const float* Wr1 = (const float*)d_in[8];
    const float* Wl2 = (const float*)d_in[9];
    const float* bl2 = (const float*)d_in[10];
    const float* Wr2 = (const float*)d_in[11];
    float* out = (float*)d_out;

    int*    cnt    = (int*)d_ws;                               // 65536 ints
    ushort* bucket = (ushort*)(cnt + 65536);                   // N_NODES_PAD*64 ushorts
    ushort* xb     = bucket + (size_t)N_NODES_PAD * BUCKET_CAP;
    ushort* h1b    = xb + (size_t)N_NODES * DIM;
    ushort* h2b    = h1b + (size_t)N_NODES * DIM;
    ushort* wb     = h2b + (size_t)N_NODES * DIM;              // 3 * 32768 bf16
    float*  pool   = (float*)(wb + 3 * DIM * KTOT);            // 8192 floats
    int*    bincnt = (int*)(pool + N_GRAPHS * DIM);            // NBINS ints
    uint*   binbuf = (uint*)(bincnt + ((NBINS + 63) & ~63));   // NBINS*BINCAP2 uints (4.4 MB)

    castx_kernel<<<(N_NODES * DIM / 4 + 255) / 256, 256, 0, stream>>>(x, xb, bincnt);
    castw_kernel<<<(3 * DIM * KTOT + 255) / 256, 256, 0, stream>>>(Wl0, Wr0, Wl1, Wr1, Wl2, Wr2, wb, pool);
    bin1_kernel<<<BIN1_GRID, BIN1_TPB, 0, stream>>>(src, dst, bincnt, binbuf);
    bin2_kernel<<<NBINS, 256, 0, stream>>>(binbuf, bincnt, bucket, cnt);

    const int lgrid = (N_NODES + 63) / 64;
    layer_fused<1, 0><<<lgrid, 512, 0, stream>>>(xb,  cnt, bucket, wb,          bl0, h1b, batch, pool);
    layer_fused<1, 0><<<lgrid, 512, 0, stream>>>(h1b, cnt, bucket, wb + 32768,  bl1, h2b, batch, pool);
    layer_fused<0, 1><<<lgrid, 512, 0, stream>>>(h2b, cnt, bucket, wb + 65536,  bl2, nullptr, batch, pool);

    pool2_kernel<<<N_GRAPHS, DIM, 0, stream>>>(pool, batch, out);
}

// Round 5
// 244.856 us; speedup vs baseline: 1.5434x; 1.1161x over previous
//
#include <hip/hip_runtime.h>

#define N_NODES 50000
#define N_EDGES 800000
#define DIM 128
#define KTOT 256        // [agg | x] concatenated along k
#define N_GRAPHS 64
#define BUCKET_CAP 64
#define LSTR 264        // LDS A-tile row stride in bf16 (+8 pad)

// edge binning: bin = dst>>7 (128 nodes/bin)
#define NBINS 391       // ceil(50000/128)
#define BINCAP2 2816    // per-bin list capacity (mean 2046, +17 sigma)
#define N_NODES_PAD (NBINS * 128)   // 50048

// bin1 geometry: 512 thr x 8 edges = 4096 edges/block -> 196 blocks
#define BIN1_TPB 512
#define BIN1_EPT 8
#define BIN1_EPB (BIN1_TPB * BIN1_EPT)
#define BIN1_GRID ((N_EDGES + BIN1_EPB - 1) / BIN1_EPB)

typedef __attribute__((ext_vector_type(8))) short bf16x8;
typedef __attribute__((ext_vector_type(16))) float f32x16;

__device__ __forceinline__ float bf2f(unsigned int u16) {
    return __uint_as_float(u16 << 16);
}
__device__ __forceinline__ unsigned short f2bf(float f) {
    unsigned int v = __float_as_uint(f);
    unsigned int r = (v + 0x7fffu + ((v >> 16) & 1u)) >> 16;   // RNE
    return (unsigned short)r;
}

// ---------- setup: casts ----------
// also zeros bincnt (must run before bin1_kernel)
__global__ void castx_kernel(const float* __restrict__ x, ushort* __restrict__ xb,
                             int* __restrict__ bincnt) {
    int i = blockIdx.x * blockDim.x + threadIdx.x;   // float4 index
    if (i < NBINS) bincnt[i] = 0;
    if (i >= N_NODES * DIM / 4) return;
    float4 v = ((const float4*)x)[i];
    ushort4 o;
    o.x = f2bf(v.x); o.y = f2bf(v.y); o.z = f2bf(v.z); o.w = f2bf(v.w);
    ((ushort4*)xb)[i] = o;
}

// wb layout per layer: [128 j][256 k] with k<128 = Wl, k>=128 = Wr. Also zeros pool.
__global__ void castw_kernel(const float* __restrict__ Wl0, const float* __restrict__ Wr0,
                             const float* __restrict__ Wl1, const float* __restrict__ Wr1,
                             const float* __restrict__ Wl2, const float* __restrict__ Wr2,
                             ushort* __restrict__ wb, float* __restrict__ pool) {
    int id = blockIdx.x * blockDim.x + threadIdx.x;   // 3*128*256 = 98304
    if (id < N_GRAPHS * DIM) pool[id] = 0.f;
    if (id >= 3 * DIM * KTOT) return;
    int l = id >> 15;
    int r = id & 32767;
    int j = r >> 8, k = r & 255;
    const float* Wl = (l == 0) ? Wl0 : (l == 1) ? Wl1 : Wl2;
    const float* Wr = (l == 0) ? Wr0 : (l == 1) ? Wr1 : Wr2;
    float v = (k < DIM) ? Wl[j * DIM + k] : Wr[j * DIM + k - DIM];
    wb[id] = f2bf(v);
}

// ---------- edge binning phase 1: LDS-ranked block partition ----------
__global__ __launch_bounds__(BIN1_TPB) void bin1_kernel(
    const int* __restrict__ src, const int* __restrict__ dst,
    int* __restrict__ bincnt, uint* __restrict__ binbuf) {
    __shared__ uint hist[NBINS];
    __shared__ uint gbase[NBINS];
    const int tid = threadIdx.x;
    for (int i = tid; i < NBINS; i += BIN1_TPB) hist[i] = 0;
    __syncthreads();

    const int e0 = blockIdx.x * BIN1_EPB + tid * BIN1_EPT;
    uint val[BIN1_EPT];
    int  bin[BIN1_EPT];
    uint rk[BIN1_EPT];

    if (e0 + BIN1_EPT <= N_EDGES) {
        int4 s0 = *(const int4*)(src + e0);
        int4 s1 = *(const int4*)(src + e0 + 4);
        int4 d0 = *(const int4*)(dst + e0);
        int4 d1 = *(const int4*)(dst + e0 + 4);
        int ss[8] = {s0.x, s0.y, s0.z, s0.w, s1.x, s1.y, s1.z, s1.w};
        int dd[8] = {d0.x, d0.y, d0.z, d0.w, d1.x, d1.y, d1.z, d1.w};
        #pragma unroll
        for (int i = 0; i < BIN1_EPT; ++i) {
            bin[i] = dd[i] >> 7;
            val[i] = (uint)ss[i] | ((uint)(dd[i] & 127) << 16);
            rk[i]  = atomicAdd(&hist[bin[i]], 1u);
        }
    } else {
        #pragma unroll
        for (int i = 0; i < BIN1_EPT; ++i) {
            if (e0 + i < N_EDGES) {
                int s = src[e0 + i], d = dst[e0 + i];
                bin[i] = d >> 7;
                val[i] = (uint)s | ((uint)(d & 127) << 16);
                rk[i]  = atomicAdd(&hist[bin[i]], 1u);
            } else {
                bin[i] = -1; val[i] = 0; rk[i] = 0;
            }
        }
    }
    __syncthreads();

    for (int i = tid; i < NBINS; i += BIN1_TPB)
        gbase[i] = (uint)atomicAdd(&bincnt[i], (int)hist[i]);
    __syncthreads();

    #pragma unroll
    for (int i = 0; i < BIN1_EPT; ++i) {
        if (bin[i] >= 0) {
            uint pos = gbase[bin[i]] + rk[i];
            if (pos < BINCAP2)
                binbuf[(size_t)bin[i] * BINCAP2 + pos] = val[i];
        }
    }
}

// ---------- edge binning phase 2: LDS bucket build, coalesced flush ----------
__global__ __launch_bounds__(256) void bin2_kernel(
    const uint* __restrict__ binbuf, const int* __restrict__ bincnt,
    ushort* __restrict__ bucket, int* __restrict__ cnt) {
    __shared__ int lcnt[128];
    __shared__ ushort lbuck[128 * BUCKET_CAP];   // 16 KB
    const int bin = blockIdx.x;
    const int tid = threadIdx.x;
    if (tid < 128) lcnt[tid] = 0;
    __syncthreads();
    int c = bincnt[bin];
    if (c > BINCAP2) c = BINCAP2;
    const uint* buf = binbuf + (size_t)bin * BINCAP2;
    for (int i = tid; i < c; i += 256) {
        uint v = buf[i];
        int ln = v >> 16;
        int pos = atomicAdd(&lcnt[ln], 1);
        if (pos < BUCKET_CAP) lbuck[ln * BUCKET_CAP + pos] = (ushort)(v & 0xffffu);
    }
    __syncthreads();
    const uint4* lb = (const uint4*)lbuck;
    uint4* gb = (uint4*)(bucket + (size_t)bin * 128 * BUCKET_CAP);
    #pragma unroll
    for (int i = tid; i < 128 * BUCKET_CAP / 8; i += 256)
        gb[i] = lb[i];
    if (tid < 128) cnt[bin * 128 + tid] = lcnt[tid];   // true degree (incl. >64 overflow)
}

// ---------- fused gather + MFMA layer ----------
// Block = 32 nodes, 256 threads (4 waves). Wave w gathers rows w*8..w*8+7 and
// computes the 32x32 output tile at col-quarter w.
// Gather: bucket row loaded with ONE wave load (b[lane]), entries broadcast
// via __shfl. CORRECTNESS RULE: every __shfl sits at a wave-uniform point —
// loop trip counts are uniform across both half-waves (main-loop condition
// uses the worst-case half; tail loop runs a uniform T with the accumulate
// predicated per-lane). A shfl inside half-divergent control flow reads
// inactive lanes -> undefined (round-4 bug).
// h-half staged to REGISTERS before the gather, ds_write after (T14).
template<int RELU, int POOL>
__global__ __launch_bounds__(256, 8) void layer_fused(
    const ushort* __restrict__ X, const int* __restrict__ cnt,
    const ushort* __restrict__ bucket, const ushort* __restrict__ wb,
    const float* __restrict__ bl, ushort* __restrict__ outb,
    const int* __restrict__ batch, float* __restrict__ pool)
{
    __shared__ ushort sA[32 * LSTR];
    const int tid = threadIdx.x;
    const int lane = tid & 63, w = tid >> 6;          // w in 0..3
    const int n0 = blockIdx.x * 32;
    const int half = lane >> 5, lcol = lane & 31;

    // ---- stage h half (k>=128) into registers; LDS write deferred ----
    const int sr0 = tid >> 4, sk0 = (tid & 15) * 8;           // rows 0..15
    const int sr1 = sr0 + 16;                                  // rows 16..31
    bf16x8 st0 = (bf16x8){0,0,0,0,0,0,0,0}, st1 = st0;
    if (n0 + sr0 < N_NODES) st0 = *(const bf16x8*)(X + (size_t)(n0 + sr0) * DIM + sk0);
    if (n0 + sr1 < N_NODES) st1 = *(const bf16x8*)(X + (size_t)(n0 + sr1) * DIM + sk0);

    // ---- degree counts for this wave's 8 rows (bucket rows padded to 50048) ----
    const int gn0 = n0 + w * 8;
    int cw = cnt[gn0 + (lane & 7)];

    // ---- gather agg half (k<128): rows in pairs, bucket prefetched ----
    for (int rp = 0; rp < 4; ++rp) {
        int beL[2];
        #pragma unroll
        for (int q = 0; q < 2; ++q)
            beL[q] = (int)bucket[(size_t)(gn0 + rp * 2 + q) * BUCKET_CAP + lane];
        #pragma unroll
        for (int q = 0; q < 2; ++q) {
            const int r8 = rp * 2 + q;
            const int row = w * 8 + r8;
            const int c = __shfl(cw, r8);                 // uniform point
            const int cl = c < BUCKET_CAP ? c : BUCKET_CAP;
            float a0 = 0.f, a1 = 0.f, a2 = 0.f, a3 = 0.f;
            int t = 0;
            // main: 4 entries/half/iter; condition 2t+7<cl is uniform and
            // guarantees validity for BOTH halves (half1's last entry 2t+7).
            for (; 2 * t + 7 < cl; t += 4) {
                int e = 2 * t + half;
                int s0 = __shfl(beL[q], e);
                int s1 = __shfl(beL[q], e + 2);
                int s2 = __shfl(beL[q], e + 4);
                int s3 = __shfl(beL[q], e + 6);
                uint2 u0 = *(const uint2*)(X + (size_t)s0 * DIM + lcol * 4);
                uint2 u1 = *(const uint2*)(X + (size_t)s1 * DIM + lcol * 4);
                uint2 u2 = *(const uint2*)(X + (size_t)s2 * DIM + lcol * 4);
                uint2 u3 = *(const uint2*)(X + (size_t)s3 * DIM + lcol * 4);
                a0 += bf2f(u0.x & 0xffff) + bf2f(u1.x & 0xffff) + bf2f(u2.x & 0xffff) + bf2f(u3.x & 0xffff);
                a1 += bf2f(u0.x >> 16)    + bf2f(u1.x >> 16)    + bf2f(u2.x >> 16)    + bf2f(u3.x >> 16);
                a2 += bf2f(u0.y & 0xffff) + bf2f(u1.y & 0xffff) + bf2f(u2.y & 0xffff) + bf2f(u3.y & 0xffff);
                a3 += bf2f(u0.y >> 16)    + bf2f(u1.y >> 16)    + bf2f(u2.y >> 16)    + bf2f(u3.y >> 16);
            }
            // tail: uniform trip count T; shfl unconditional (index <= 63),
            // load+accumulate predicated per-lane (no cross-lane op inside).
            const int T = (cl + 1) >> 1;
            for (; t < T; ++t) {
                int e = 2 * t + half;
                int s0 = __shfl(beL[q], e);
                if (e < cl) {
                    uint2 u0 = *(const uint2*)(X + (size_t)s0 * DIM + lcol * 4);
                    a0 += bf2f(u0.x & 0xffff);
                    a1 += bf2f(u0.x >> 16);
                    a2 += bf2f(u0.y & 0xffff);
                    a3 += bf2f(u0.y >> 16);
                }
            }
            a0 += __shfl_xor(a0, 32);
            a1 += __shfl_xor(a1, 32);
            a2 += __shfl_xor(a2, 32);
            a3 += __shfl_xor(a3, 32);
            if (half == 0) {
                float inv = 1.0f / (float)(c > 0 ? c : 1);
                uint2 o;
                o.x = ((unsigned int)f2bf(a1 * inv) << 16) | f2bf(a0 * inv);
                o.y = ((unsigned int)f2bf(a3 * inv) << 16) | f2bf(a2 * inv);
                *(uint2*)(&sA[row * LSTR + lcol * 4]) = o;
            }
        }
    }

    // ---- deferred h-half LDS write (stage loads long since landed) ----
    *(bf16x8*)(&sA[sr0 * LSTR + DIM + sk0]) = st0;
    *(bf16x8*)(&sA[sr1 * LSTR + DIM + sk0]) = st1;
    __syncthreads();

    // ---- MFMA: wave w computes rows 0..31 x cols w*32..w*32+31 ----
    // W frags loaded on the fly (L2-hot): lane l needs W[w*32+(l&31)][kt*16+(l>>5)*8..]
    const ushort* wp = wb + (size_t)(w * 32 + (lane & 31)) * KTOT + (lane >> 5) * 8;
    const int arow = lane & 31;
    const int akoff = (lane >> 5) * 8;
    f32x16 acc = {};
    #pragma unroll
    for (int kt = 0; kt < 16; ++kt) {
        bf16x8 a = *(const bf16x8*)(&sA[arow * LSTR + kt * 16 + akoff]);
        bf16x8 bwf = *(const bf16x8*)(wp + kt * 16);
        acc = __builtin_amdgcn_mfma_f32_32x32x16_bf16(a, bwf, acc, 0, 0, 0);
    }

    // C/D map: col=lane&31, row=(reg&3)+8*(reg>>2)+4*(lane>>5)  [m74/m101]
    const int j = w * 32 + (lane & 31);
    const float bias = bl[j];
    if (POOL) {
        // rows ascend with r -> run-flush per graph segment (batch sorted)
        float run = 0.f; int gcur = -1;
        #pragma unroll
        for (int r = 0; r < 16; ++r) {
            int row = (r & 3) + 8 * (r >> 2) + 4 * (lane >> 5);
            int gn = n0 + row;
            if (gn < N_NODES) {
                float v = acc[r] + bias;
                int g = batch[gn];
                if (g != gcur) {
                    if (gcur >= 0) unsafeAtomicAdd(&pool[gcur * DIM + j], run);
                    run = 0.f; gcur = g;
                }
                run += v;
            }
        }
        if (gcur >= 0) unsafeAtomicAdd(&pool[gcur * DIM + j], run);
    } else {
        #pragma unroll
        for (int r = 0; r < 16; ++r) {
            int row = (r & 3) + 8 * (r >> 2) + 4 * (lane >> 5);
            int gn = n0 + row;
            if (gn < N_NODES) {
                float v = acc[r] + bias;
                if (RELU) v = fmaxf(v, 0.f);
                outb[(size_t)gn * DIM + j] = f2bf(v);
            }
        }
    }
}

// ---------- pool finalize ----------
__global__ void pool2_kernel(const float* __restrict__ pool, const int* __restrict__ batch,
                             float* __restrict__ out) {
    int g = blockIdx.x;
    int j = threadIdx.x;
    int lo = 0, hi = N_NODES;
    while (lo < hi) { int m = (lo + hi) >> 1; if (batch[m] < g) lo = m + 1; else hi = m; }
    int start = lo;
    lo = start; hi = N_NODES;
    while (lo < hi) { int m = (lo + hi) >> 1; if (batch[m] < g + 1) lo = m + 1; else hi = m; }
    int cnt = lo - start;
    out[g * DIM + j] = pool[g * DIM + j] / (float)(cnt > 0 ? cnt : 1);
}

extern "C" void kernel_launch(void* const* d_in, const int* in_sizes, int n_in,
                              void* d_out, int out_size, void* d_ws, size_t ws_size,
                              hipStream_t stream) {
    const float* x    = (const float*)d_in[0];
    const int*   ei   = (const int*)d_in[1];
    const int*   src  = ei;
    const int*   dst  = ei + N_EDGES;
    const int*   batch = (const int*)d_in[2];
    const float* Wl0 = (const float*)d_in[3];
    const float* bl0 = (const float*)d_in[4];
    const float* Wr0 = (const float*)d_in[5];
    const float* Wl1 = (const float*)d_in[6];
    const float* bl1 = (const float*)d_in[7];
    const float* Wr1 = (const float*)d_in[8];
    const float* Wl2 = (const float*)d_in[9];
    const float* bl2 = (const float*)d_in[10];
    const float* Wr2 = (const float*)d_in[11];
    float* out = (float*)d_out;

    int*    cnt    = (int*)d_ws;                               // 65536 ints
    ushort* bucket = (ushort*)(cnt + 65536);                   // N_NODES_PAD*64 ushorts
    ushort* xb     = bucket + (size_t)N_NODES_PAD * BUCKET_CAP;
    ushort* h1b    = xb + (size_t)N_NODES * DIM;
    ushort* h2b    = h1b + (size_t)N_NODES * DIM;
    ushort* wb     = h2b + (size_t)N_NODES * DIM;              // 3 * 32768 bf16
    float*  pool   = (float*)(wb + 3 * DIM * KTOT);            // 8192 floats
    int*    bincnt = (int*)(pool + N_GRAPHS * DIM);            // NBINS ints
    uint*   binbuf = (uint*)(bincnt + ((NBINS + 63) & ~63));   // NBINS*BINCAP2 uints (4.4 MB)

    castx_kernel<<<(N_NODES * DIM / 4 + 255) / 256, 256, 0, stream>>>(x, xb, bincnt);
    castw_kernel<<<(3 * DIM * KTOT + 255) / 256, 256, 0, stream>>>(Wl0, Wr0, Wl1, Wr1, Wl2, Wr2, wb, pool);
    bin1_kernel<<<BIN1_GRID, BIN1_TPB, 0, stream>>>(src, dst, bincnt, binbuf);
    bin2_kernel<<<NBINS, 256, 0, stream>>>(binbuf, bincnt, bucket, cnt);

    const int lgrid = (N_NODES + 31) / 32;
    layer_fused<1, 0><<<lgrid, 256, 0, stream>>>(xb,  cnt, bucket, wb,          bl0, h1b, batch, pool);
    layer_fused<1, 0><<<lgrid, 256, 0, stream>>>(h1b, cnt, bucket, wb + 32768,  bl1, h2b, batch, pool);
    layer_fused<0, 1><<<lgrid, 256, 0, stream>>>(h2b, cnt, bucket, wb + 65536,  bl2, nullptr, batch, pool);

    pool2_kernel<<<N_GRAPHS, DIM, 0, stream>>>(pool, batch, out);
}